// Round 9
// baseline (123.158 us; speedup 1.0000x reference)
//
#include <hip/hip_runtime.h>
#include <hip/hip_bf16.h>

// NT-Xent loss, N=4096, D=256, fp32 inputs, fp32 scalar output.
// loss = mean_i [ log( sum_{j != i} exp(2*cos(zn_i, zn_j)) ) - 2*cos(zn_i, zn_pair(i)) ]
//
// v9: gram ported to the m201 shape (the proven step past the m97-class
// ceiling): 256 blocks (1/CU) x 512 thr (8 waves), 256-row tiles, 4x32KB LDS
// ring, prefetch distance 2 iters, PRECISE counted vmcnt (16/12/8).
// r8 post-mortem: r1's full gram ran at 793 TF = ~88% of the m97-structure
// ceiling; symmetric gram is ~21-25us hidden under the 42.6us fill cutoff.
// Col atomics made uniform (diag adds 0.0f) so vmcnt counts are data-indep.

#define NROWS 8192
#define NHALF 4096
#define DDIM  256
#define GBLK  256   // 32 I-tiles x 8 chunks

typedef __bf16 bf16;
typedef __bf16 bf16x4 __attribute__((ext_vector_type(4)));
typedef __bf16 bf16x8 __attribute__((ext_vector_type(8)));
typedef float  f32x4  __attribute__((ext_vector_type(4)));

__constant__ const float kTwoLog2e = 2.8853900817779268f;  // 2*log2(e): exp(2x)=exp2(kTwoLog2e*x)
__constant__ const float kLn2      = 0.6931471805599453f;

__device__ __forceinline__ const float* zrow(const float* z1, const float* z2, int r) {
  return (r < NHALF) ? (z1 + (size_t)r * DDIM) : (z2 + (size_t)(r - NHALF) * DDIM);
}

typedef const __attribute__((address_space(1))) unsigned int* as1_u32p;
typedef __attribute__((address_space(3))) unsigned int* as3_u32p;

__device__ __forceinline__ void load_lds16(const void* g, void* l) {
  __builtin_amdgcn_global_load_lds((as1_u32p)g, (as3_u32p)l, 16, 0, 0);
}

// ---------------- k1: normalize ----------------
__global__ void k_normalize(const float* __restrict__ z1, const float* __restrict__ z2,
                            bf16* __restrict__ zn, float* __restrict__ invn,
                            float* __restrict__ rowsum, float* __restrict__ out) {
  const int wave = threadIdx.x >> 6, lane = threadIdx.x & 63;
  const int row = blockIdx.x * 4 + wave;
  f32x4 v = *(const f32x4*)(zrow(z1, z2, row) + lane * 4);
  float ss = v.x * v.x + v.y * v.y + v.z * v.z + v.w * v.w;
#pragma unroll
  for (int off = 1; off < 64; off <<= 1) ss += __shfl_xor(ss, off);
  const float inv = 1.0f / fmaxf(sqrtf(ss), 1e-8f);
  bf16x4 o;
  o.x = (bf16)(v.x * inv); o.y = (bf16)(v.y * inv);
  o.z = (bf16)(v.z * inv); o.w = (bf16)(v.w * inv);
  *(bf16x4*)(zn + (size_t)row * DDIM + lane * 4) = o;
  if (lane == 0) { invn[row] = inv; rowsum[row] = 0.0f; }
  if (blockIdx.x == 0 && threadIdx.x == 0) out[0] = 0.0f;
}

// ---------------- k2: circulant symmetric Gram, m201 shape ----------------
// Block (I, chunk): I in [0,32) row-tile of 256 (8 waves x 32 rows, A in regs);
// chunk in [0,8) covers d in {2c, 2c+1} (+d=16 for chunk7 & I<16). J=(I+d)&31;
// each J-tile = 4 LDS-iters of 64 cols -> n = 8 (or 12). Coverage: pair {I,J}
// with delta=(J-I)%32: delta<=15 counted from the I side once; delta=16 once
// via I<16; delta>=17 from the J side once. d=0 diag: row-sums only (col
// atomic adds 0.0f to keep the VMEM instruction stream uniform).
//
// Pipeline: 4x32KB LDS ring. Per-wave VMEM issue order:
//   prologue [D0:4][A:16][D1:4][D2:4]; iter t: wait; consume{..4 col atomics};
//   barrier; issue D(t+3):4 (if t+3<n).
// Precise waits (counts verified against this exact order):
//   t=0: outstanding D0,A,D1,D2 -> need D0+A -> leave 8  -> vmcnt(8)
//   t=1: D1,D2,A0,D3 (16)       -> need D1   -> leave 12 -> vmcnt(12)
//   2<=t<=n-3: D(t),A(t-2),D(t+1),A(t-1),D(t+2) (20) -> leave 16 -> vmcnt(16)
//   t=n-2: D(n-2),A(n-4),D(n-1),A(n-3) (16) -> leave 12 -> vmcnt(12)
//   t=n-1: [A..],D(n-1),A,A -> leave 8 -> vmcnt(8)
// Prefetch distance = 2 full iters (vs 1 in r8); atomics get >=1 iter slack.
__global__ __launch_bounds__(512, 2) void k_gram(const bf16* __restrict__ zn,
                                                 float* __restrict__ rowsum) {
  __shared__ __align__(16) unsigned char ldsb[4][64 * 512];  // 128KB ring
  const int tid  = threadIdx.x;
  const int wave = tid >> 6, lane = tid & 63;
  const int quad = lane >> 4, l15 = lane & 15;

  const int I      = blockIdx.x >> 3;   // [0,32)
  const int chunk  = blockIdx.x & 7;    // [0,8)
  const int base_d = chunk * 2;
  const int n      = (chunk == 7 && I < 16) ? 12 : 8;  // 64-col LDS-iters
  const int R0     = I * 256 + wave * 32;

  auto cbase = [&](int t) -> int {
    const int d = base_d + (t >> 2);          // t in [8,12) -> d=16 (chunk7)
    const int J = (I + d) & 31;
    return J * 256 + (t & 3) * 64;
  };
  auto issue_dma = [&](int t, int b) {
    const unsigned char* s = (const unsigned char*)(zn + (size_t)cbase(t) * DDIM);
#pragma unroll
    for (int j = 0; j < 4; ++j) {
      const int p = (wave * 4 + j) * 64 + lane;  // 16B-chunk position 0..2047
      const int r = p >> 5;                      // staged col-row 0..63
      const int q = (p & 31) ^ (r & 15);         // swizzle inverse on SOURCE
      load_lds16(s + r * 512 + q * 16, &ldsb[b][(wave * 4 + j) * 1024]);
    }
  };

  // pinned prologue issue order: [D0 x4] [A x16] [D1 x4] [D2 x4]
  issue_dma(0, 0);
  __builtin_amdgcn_sched_barrier(0);

  bf16x8 a[2][8];
#pragma unroll
  for (int s = 0; s < 2; ++s) {
    const bf16x8* ap = (const bf16x8*)(zn + (size_t)(R0 + s * 16 + l15) * DDIM);
#pragma unroll
    for (int kk = 0; kk < 8; ++kk) a[s][kk] = ap[kk * 4 + quad];
  }
  __builtin_amdgcn_sched_barrier(0);

  issue_dma(1, 1);
  issue_dma(2, 2);
  __builtin_amdgcn_sched_barrier(0);

  float sum[2][4] = {{0.f, 0.f, 0.f, 0.f}, {0.f, 0.f, 0.f, 0.f}};
  const f32x4 zero4 = {0.f, 0.f, 0.f, 0.f};

  for (int t = 0; t < n; ++t) {
    const int wc = (t == 0) ? 8 : (t == 1 || t == n - 2) ? 12 : (t == n - 1) ? 8 : 16;
    if (wc == 8)       asm volatile("s_waitcnt vmcnt(8)" ::: "memory");
    else if (wc == 12) asm volatile("s_waitcnt vmcnt(12)" ::: "memory");
    else               asm volatile("s_waitcnt vmcnt(16)" ::: "memory");
    __builtin_amdgcn_s_barrier();        // all waves' DMA for tile t complete
    __builtin_amdgcn_sched_barrier(0);   // no ds_read hoisting above barrier

    const unsigned char* bp = ldsb[t & 3];

    f32x4 acc[2][4];
#pragma unroll
    for (int s = 0; s < 2; ++s)
#pragma unroll
      for (int cs = 0; cs < 4; ++cs) acc[s][cs] = zero4;

    __builtin_amdgcn_s_setprio(1);
#pragma unroll
    for (int kk = 0; kk < 8; ++kk) {
      bf16x8 b[4];
#pragma unroll
      for (int cs = 0; cs < 4; ++cs) {
        const int rb = cs * 16 + l15;                // staged col-row 0..63
        const int sl = (kk * 4 + quad) ^ (rb & 15);  // swizzled chunk slot
        b[cs] = *(const bf16x8*)(bp + rb * 512 + sl * 16);
      }
#pragma unroll
      for (int s = 0; s < 2; ++s)
#pragma unroll
        for (int cs = 0; cs < 4; ++cs)
          acc[s][cs] =
              __builtin_amdgcn_mfma_f32_16x16x32_bf16(a[s][kk], b[cs], acc[s][cs], 0, 0, 0);
    }
    __builtin_amdgcn_s_setprio(0);

    // exp + row accumulation + UNIFORM col atomics (diag contributes 0.0f so
    // the per-iter VMEM instruction count is constant -> waits stay sound)
    const bool dg = (chunk == 0 && t < 4);  // d==0 diagonal tile
    const int cb = cbase(t);
#pragma unroll
    for (int cs = 0; cs < 4; ++cs) {
      float c = 0.f;
#pragma unroll
      for (int s = 0; s < 2; ++s)
#pragma unroll
        for (int r = 0; r < 4; ++r) {
          const float e = __builtin_amdgcn_exp2f(acc[s][cs][r] * kTwoLog2e);
          sum[s][r] += e;
          c += e;
        }
      c += __shfl_xor(c, 16); c += __shfl_xor(c, 32);  // cross-quad col sum
      if (quad == 0) atomicAdd(&rowsum[cb + cs * 16 + l15], dg ? 0.0f : c);
    }

    __builtin_amdgcn_s_barrier();        // all waves done READING tile t
    __builtin_amdgcn_sched_barrier(0);
    if (t + 3 < n) {
      issue_dma(t + 3, (t + 3) & 3);     // ring slot (t+3)&3 = (t-1)&3: freed
      __builtin_amdgcn_sched_barrier(0);
    }
  }

  // row-sums (wave-exclusive rows): C/D layout (m89): row=quad*4+r, col=l15
#pragma unroll
  for (int s = 0; s < 2; ++s)
#pragma unroll
    for (int r = 0; r < 4; ++r) {
      float v = sum[s][r];
      v += __shfl_xor(v, 1); v += __shfl_xor(v, 2);
      v += __shfl_xor(v, 4); v += __shfl_xor(v, 8);
      if (l15 == 0) atomicAdd(&rowsum[R0 + s * 16 + quad * 4 + r], v);
    }
}

// ---------------- k3: per-row contribution + fused reduce ----------------
__global__ void k_finalize(const float* __restrict__ z1, const float* __restrict__ z2,
                           const bf16* __restrict__ zn, const float* __restrict__ invn,
                           const float* __restrict__ rowsum, float* __restrict__ out) {
  const int wave = threadIdx.x >> 6, lane = threadIdx.x & 63;
  const int row = blockIdx.x * 4 + wave;
  const int pr = (row < NHALF) ? row + NHALF : row - NHALF;

  f32x4 a4 = *(const f32x4*)(zrow(z1, z2, row) + lane * 4);
  f32x4 b4 = *(const f32x4*)(zrow(z1, z2, pr) + lane * 4);
  bf16x4 nb = *(const bf16x4*)(zn + (size_t)row * DDIM + lane * 4);

  float pd = a4.x * b4.x + a4.y * b4.y + a4.z * b4.z + a4.w * b4.w;
  float f0 = (float)nb.x, f1 = (float)nb.y, f2 = (float)nb.z, f3 = (float)nb.w;
  float nd = f0 * f0 + f1 * f1 + f2 * f2 + f3 * f3;
#pragma unroll
  for (int off = 1; off < 64; off <<= 1) {
    pd += __shfl_xor(pd, off);
    nd += __shfl_xor(nd, off);
  }
  __shared__ float wsum[4];
  if (lane == 0) {
    const float p = 2.0f * pd * invn[row] * invn[pr];              // exact fp32 pair sim
    const float dexp = __builtin_amdgcn_exp2f(kTwoLog2e * nd);     // Gram's diagonal term
    const float lse = __builtin_amdgcn_logf(rowsum[row] - dexp) * kLn2;
    wsum[wave] = lse - p;
  }
  __syncthreads();
  if (threadIdx.x == 0)
    atomicAdd(out, (wsum[0] + wsum[1] + wsum[2] + wsum[3]) * (1.0f / (float)NROWS));
}

extern "C" void kernel_launch(void* const* d_in, const int* in_sizes, int n_in,
                              void* d_out, int out_size, void* d_ws, size_t ws_size,
                              hipStream_t stream) {
  const float* z1 = (const float*)d_in[0];
  const float* z2 = (const float*)d_in[1];
  unsigned char* ws = (unsigned char*)d_ws;

  // ws layout: zn bf16 [8192*256] (4 MB) | invn f32[8192] | rowsum f32[8192]
  bf16* zn = (bf16*)ws;
  float* invn = (float*)(ws + (size_t)NROWS * DDIM * sizeof(bf16));
  float* rowsum = invn + NROWS;
  float* out = (float*)d_out;

  hipLaunchKernelGGL(k_normalize, dim3(NROWS / 4), dim3(256), 0, stream, z1, z2, zn, invn, rowsum,
                     out);
  hipLaunchKernelGGL(k_gram, dim3(GBLK), dim3(512), 0, stream, zn, rowsum);
  hipLaunchKernelGGL(k_finalize, dim3(NROWS / 4), dim3(256), 0, stream, z1, z2, zn, invn, rowsum,
                     out);
}